// Round 7
// baseline (2610.376 us; speedup 1.0000x reference)
//
#include <hip/hip_runtime.h>
#include <cstdint>
#include <cstddef>

// Shapes (fixed): B=64, N=4, P=128, d=h=256, totP=512, feat=131072
#define P_    128
#define H_    256
#define FEAT_ 131072

// ---------------------------------------------------------------------------
// xn: row-normalize x. One block per row (32768 rows), 64 threads, LDS tree.
// ---------------------------------------------------------------------------
__global__ __launch_bounds__(64) void k_xn(
    const float* __restrict__ x, float* __restrict__ xn) {
  __shared__ float red[64];
  const int row = blockIdx.x, t = threadIdx.x;
  const float* xr = x + (size_t)row * 256;
  float ss = 0.f;
  for (int d = t; d < 256; d += 64) { float v = xr[d]; ss += v * v; }
  red[t] = ss; __syncthreads();
  for (int s = 32; s; s >>= 1) { if (t < s) red[t] += red[t + s]; __syncthreads(); }
  const float inv = 1.0f / fmaxf(sqrtf(red[0]), 1e-12f);
  for (int d = t; d < 256; d += 64) xn[(size_t)row * 256 + d] = xr[d] * inv;
}

// ---------------------------------------------------------------------------
// sim: raw[blk][p][q] = (p==q) ? 0 : ((xn_p . xn_q)+1)*0.5*mask[p][q]
// ---------------------------------------------------------------------------
__global__ __launch_bounds__(128) void k_sim(
    const float* __restrict__ xn, const float* __restrict__ mask,
    float* __restrict__ An) {
  const int blk = blockIdx.x, p = blockIdx.y, q = threadIdx.x;
  const float* xp = xn + (size_t)blk * (128 * 256) + (size_t)p * 256;
  const float* xq = xn + (size_t)blk * (128 * 256) + (size_t)q * 256;
  float dot = 0.f;
  for (int d = 0; d < 256; ++d) dot += xp[d] * xq[d];
  float v = (dot + 1.0f) * 0.5f * mask[p * 128 + q];
  An[(size_t)blk * 16384 + p * 128 + q] = (p == q) ? 0.0f : v;
}

// ---------------------------------------------------------------------------
// deg/dinv: deg[blk][p] = 1 + sum_q raw ; dinv = rsqrt(max(deg,eps))
// ---------------------------------------------------------------------------
__global__ __launch_bounds__(128) void k_deg(
    const float* __restrict__ An, float* __restrict__ dinv) {
  __shared__ float red[128];
  const int blk = blockIdx.x, p = blockIdx.y, q = threadIdx.x;
  red[q] = An[(size_t)blk * 16384 + p * 128 + q];
  __syncthreads();
  for (int s = 64; s; s >>= 1) { if (q < s) red[q] += red[q + s]; __syncthreads(); }
  if (q == 0) {
    float deg = 1.0f + red[0];
    dinv[blk * 128 + p] = (deg > 0.0f) ? rsqrtf(fmaxf(deg, 1e-12f)) : 0.0f;
  }
}

// ---------------------------------------------------------------------------
// An normalize: An[p][q] = dinv_p * A[p][q] * dinv_q  (A = raw + I)
// ---------------------------------------------------------------------------
__global__ __launch_bounds__(128) void k_annorm(
    float* __restrict__ An, const float* __restrict__ dinv) {
  const int blk = blockIdx.x, p = blockIdx.y, q = threadIdx.x;
  const size_t i = (size_t)blk * 16384 + p * 128 + q;
  const float dp = dinv[blk * 128 + p], dq = dinv[blk * 128 + q];
  An[i] = (p == q) ? dp * dq : An[i] * dp * dq;
}

// ---------------------------------------------------------------------------
// gemm: out[m][c] = sum_k A[m][k] * W[k][c] + bias[c]   (M=32768, N=K=256)
// ---------------------------------------------------------------------------
__global__ __launch_bounds__(256) void k_gemm(
    const float* __restrict__ A, const float* __restrict__ W,
    const float* __restrict__ bias, float* __restrict__ out) {
  const int m = blockIdx.x, c = threadIdx.x;
  const float* ar = A + (size_t)m * 256;
  float acc = bias[c];
  for (int k = 0; k < 256; ++k) acc += ar[k] * W[k * 256 + c];
  out[(size_t)m * 256 + c] = acc;
}

// ---------------------------------------------------------------------------
// bmm: out[blk*128+p][c] = sum_q An[blk][p][q] * XW[blk*128+q][c]
// ---------------------------------------------------------------------------
__global__ __launch_bounds__(256) void k_bmm(
    const float* __restrict__ An, const float* __restrict__ XW,
    float* __restrict__ out) {
  const int blk = blockIdx.x, p = blockIdx.y, c = threadIdx.x;
  const float* ar = An + (size_t)blk * 16384 + p * 128;
  const float* xb = XW + (size_t)blk * (128 * 256);
  float acc = 0.f;
  for (int q = 0; q < 128; ++q) acc += ar[q] * xb[(size_t)q * 256 + c];
  out[(size_t)(blk * 128 + p) * 256 + c] = acc;
}

// ---------------------------------------------------------------------------
// bn_stats: per-channel sum & sumsq over 32768 rows, deterministic.
// ---------------------------------------------------------------------------
__global__ __launch_bounds__(256) void k_bnstats(
    const float* __restrict__ pre, float* __restrict__ st) {
  __shared__ float rs[256], rs2[256];
  const int c = blockIdx.x, t = threadIdx.x;
  float s = 0.f, s2 = 0.f;
  for (int r = t; r < 32768; r += 256) {
    float v = pre[(size_t)r * 256 + c];
    s += v; s2 += v * v;
  }
  rs[t] = s; rs2[t] = s2; __syncthreads();
  for (int k = 128; k; k >>= 1) {
    if (t < k) { rs[t] += rs[t + k]; rs2[t] += rs2[t + k]; }
    __syncthreads();
  }
  if (t == 0) { st[c] = rs[0]; st[256 + c] = rs2[0]; }
}

// ---------------------------------------------------------------------------
// bn_apply: out = relu(g*(pre-m)/sqrt(v+eps)+be), out-of-place.
// ---------------------------------------------------------------------------
__global__ __launch_bounds__(256) void k_bnapply(
    const float* __restrict__ pre, const float* __restrict__ st,
    const float* __restrict__ g, const float* __restrict__ be,
    float* __restrict__ out) {
  const int r = blockIdx.x, c = threadIdx.x;
  const float m = st[c] * (1.0f / 32768.0f);
  const float var = st[256 + c] * (1.0f / 32768.0f) - m * m;
  const float sc = g[c] * rsqrtf(var + 1e-5f);
  const float sh = be[c] - m * sc;
  const size_t i = (size_t)r * 256 + c;
  out[i] = fmaxf(pre[i] * sc + sh, 0.0f);
}

__global__ __launch_bounds__(256) void k_zero(float* __restrict__ z1) {
  z1[blockIdx.x * 256 + threadIdx.x] = 0.0f;
}

// ---------------------------------------------------------------------------
// head split-K GEMM: z1[64][128] += graph[64][131072] @ Wm1[131072][128]
// (bm1 = zeros and cancels under batch-BN.)
// ---------------------------------------------------------------------------
__global__ __launch_bounds__(256) void k_headgemm(
    const float* __restrict__ graph, const float* __restrict__ Wm1,
    float* __restrict__ z1) {
  const int t = threadIdx.x;
  const int hg = t & 31;   // cols hg*4..+3
  const int bg = t >> 5;   // rows bg*8..+7
  float acc[8][4];
  #pragma unroll
  for (int i = 0; i < 8; ++i)
    #pragma unroll
    for (int j = 0; j < 4; ++j) acc[i][j] = 0.f;
  const int k0 = blockIdx.x * 1024;
  for (int kk = 0; kk < 1024; ++kk) {
    const int k = k0 + kk;
    float4 wv = *(const float4*)(Wm1 + (size_t)k * 128 + hg * 4);
    #pragma unroll
    for (int i = 0; i < 8; ++i) {
      float a = graph[(size_t)(bg * 8 + i) * FEAT_ + k];
      acc[i][0] += a * wv.x; acc[i][1] += a * wv.y;
      acc[i][2] += a * wv.z; acc[i][3] += a * wv.w;
    }
  }
  #pragma unroll
  for (int i = 0; i < 8; ++i)
    #pragma unroll
    for (int j = 0; j < 4; ++j)
      atomicAdd(&z1[(bg * 8 + i) * 128 + hg * 4 + j], acc[i][j]);
}

// ---------------------------------------------------------------------------
// head BN over batch (J features) + ReLU
// ---------------------------------------------------------------------------
template <int J>
__global__ __launch_bounds__(64) void k_headbn(
    const float* __restrict__ z, const float* __restrict__ g,
    const float* __restrict__ be, float* __restrict__ zr) {
  __shared__ float rs[64], rs2[64];
  const int j = blockIdx.x, b = threadIdx.x;
  const float v = z[b * J + j];
  rs[b] = v; rs2[b] = v * v; __syncthreads();
  for (int s = 32; s; s >>= 1) {
    if (b < s) { rs[b] += rs[b + s]; rs2[b] += rs2[b + s]; }
    __syncthreads();
  }
  const float m = rs[0] * (1.0f / 64.0f);
  const float var = rs2[0] * (1.0f / 64.0f) - m * m;
  const float sc = g[j] * rsqrtf(var + 1e-5f);
  const float sh = be[j] - m * sc;
  zr[b * J + j] = fmaxf(v * sc + sh, 0.0f);
}

// ---------------------------------------------------------------------------
// z2[b][j] = sum_k zr1[b][k] * Wm2[k][j]   (bm2 = zeros, cancels under BN)
// ---------------------------------------------------------------------------
__global__ __launch_bounds__(64) void k_headmm2(
    const float* __restrict__ zr1, const float* __restrict__ Wm2,
    float* __restrict__ z2) {
  const int b = blockIdx.x, j = threadIdx.x;
  float acc = 0.f;
  for (int k = 0; k < 128; ++k) acc += zr1[b * 128 + k] * Wm2[k * 64 + j];
  z2[b * 64 + j] = acc;
}

// ---------------------------------------------------------------------------
// out[b][c] = sum_k zr2[b][k] * Wm3[k][c] + bm3[c]   *** f32 store ***
// ---------------------------------------------------------------------------
__global__ __launch_bounds__(128) void k_headout(
    const float* __restrict__ zr2, const float* __restrict__ Wm3,
    const float* __restrict__ bm3, float* __restrict__ out) {
  const int t = threadIdx.x;
  const int b = t >> 1, c = t & 1;
  float s = bm3[c];
  for (int k = 0; k < 64; ++k) s += zr2[b * 64 + k] * Wm3[k * 2 + c];
  out[t] = s;
}

// ---------------------------------------------------------------------------
extern "C" void kernel_launch(void* const* d_in, const int* in_sizes, int n_in,
                              void* d_out, int out_size, void* d_ws, size_t ws_size,
                              hipStream_t stream) {
  (void)in_sizes; (void)n_in; (void)out_size; (void)ws_size;
  const float* x    = (const float*)d_in[0];
  const float* mask = (const float*)d_in[1];
  const float* W1   = (const float*)d_in[2];
  const float* b1   = (const float*)d_in[3];
  const float* g1   = (const float*)d_in[4];
  const float* be1  = (const float*)d_in[5];
  const float* W2   = (const float*)d_in[6];
  const float* b2   = (const float*)d_in[7];
  const float* g2   = (const float*)d_in[8];
  const float* be2  = (const float*)d_in[9];
  const float* Wm1  = (const float*)d_in[10];
  // d_in[11] = bm1 (zeros; cancels under BN)
  const float* gm1  = (const float*)d_in[12];
  const float* bem1 = (const float*)d_in[13];
  const float* Wm2  = (const float*)d_in[14];
  // d_in[15] = bm2 (zeros; cancels under BN)
  const float* gm2  = (const float*)d_in[16];
  const float* bem2 = (const float*)d_in[17];
  const float* Wm3  = (const float*)d_in[18];
  const float* bm3  = (const float*)d_in[19];

  // workspace (floats), total 29,418,496 f = 117.67 MB (probe-verified fits)
  float* ws   = (float*)d_ws;
  float* T1   = ws;                 // 8,388,608 : xn -> h1 -> h2
  float* An   = T1 + 8388608;       // 4,194,304
  float* T2   = An + 4194304;       // 8,388,608 : XW1 -> XW2
  float* T3   = T2 + 8388608;       // 8,388,608 : pre1 -> pre2
  float* z1   = T3 + 8388608;       // 8,192
  float* dinv = z1 + 8192;          // 32,768
  float* st1  = dinv + 32768;       // 512
  float* st2  = st1 + 512;          // 512
  float* zr1  = st2 + 512;          // 8,192
  float* z2   = zr1 + 8192;         // 4,096
  float* zr2  = z2 + 4096;          // 4,096

  // edges / An
  k_xn<<<32768, 64, 0, stream>>>(x, T1);
  k_sim<<<dim3(256, 128), 128, 0, stream>>>(T1, mask, An);
  k_deg<<<dim3(256, 128), 128, 0, stream>>>(An, dinv);
  k_annorm<<<dim3(256, 128), 128, 0, stream>>>(An, dinv);

  // layer 1
  k_gemm<<<32768, 256, 0, stream>>>(x, W1, b1, T2);
  k_bmm<<<dim3(256, 128), 256, 0, stream>>>(An, T2, T3);
  k_bnstats<<<256, 256, 0, stream>>>(T3, st1);
  k_bnapply<<<32768, 256, 0, stream>>>(T3, st1, g1, be1, T1);   // h1

  // layer 2
  k_gemm<<<32768, 256, 0, stream>>>(T1, W2, b2, T2);
  k_bmm<<<dim3(256, 128), 256, 0, stream>>>(An, T2, T3);
  k_bnstats<<<256, 256, 0, stream>>>(T3, st2);
  k_bnapply<<<32768, 256, 0, stream>>>(T3, st2, g2, be2, T1);   // h2

  // head
  k_zero<<<32, 256, 0, stream>>>(z1);
  k_headgemm<<<128, 256, 0, stream>>>(T1, Wm1, z1);
  k_headbn<128><<<128, 64, 0, stream>>>(z1, gm1, bem1, zr1);
  k_headmm2<<<64, 64, 0, stream>>>(zr1, Wm2, z2);
  k_headbn<64><<<64, 64, 0, stream>>>(z2, gm2, bem2, zr2);
  k_headout<<<1, 128, 0, stream>>>(zr2, Wm3, bm3, (float*)d_out);
}